// Round 1
// baseline (881.821 us; speedup 1.0000x reference)
//
#include <hip/hip_runtime.h>

// ExpertModuleTrm: B=16, L=2048, D=400, HS=100, heads=4 (identical -> 1 head).
// Pipeline: dsum -> W=dsum@w2 -> QKV gemm -> flash attention -> h=relu(head@W+b2)
//           + max/mean pool partials -> final reduce + 2-layer MLP.
// All fp32 vector-FMA (no fp32 MFMA on CDNA4; bf16 rounding too risky vs 1e-2 absmax).

#define L_SEQ 2048
#define HS    100
#define ATT_SCALE 0.1f

__device__ __forceinline__ void load4(float (&d)[4], const float* p) {
    float4 t = *reinterpret_cast<const float4*>(p);
    d[0] = t.x; d[1] = t.y; d[2] = t.z; d[3] = t.w;
}

// ---------------- kernel 0a: dsum[i,j] = sum_r dense[i+100r, j] ----------------
__global__ void k_dsum(const float* __restrict__ dense, float* __restrict__ dsum) {
    int t = blockIdx.x * 256 + threadIdx.x;
    if (t < 40000)
        dsum[t] = dense[t] + dense[t + 40000] + dense[t + 80000] + dense[t + 120000];
}

// ---------------- kernel 0b: W = dsum @ w2   [100,400]x[400,400] ----------------
__global__ __launch_bounds__(256)
void k_w(const float* __restrict__ dsum, const float* __restrict__ w2,
         float* __restrict__ W) {
    __shared__ float rows[4 * 400];
    const int r0 = blockIdx.x * 4;
    for (int i = threadIdx.x; i < 1600; i += 256) rows[i] = dsum[r0 * 400 + i];
    __syncthreads();
    for (int c = threadIdx.x; c < 400; c += 256) {
        float a0 = 0.f, a1 = 0.f, a2 = 0.f, a3 = 0.f;
#pragma unroll 4
        for (int k = 0; k < 400; ++k) {
            float wv = w2[k * 400 + c];
            a0 += rows[k] * wv;        a1 += rows[400 + k] * wv;
            a2 += rows[800 + k] * wv;  a3 += rows[1200 + k] * wv;
        }
        W[(r0 + 0) * 400 + c] = a0; W[(r0 + 1) * 400 + c] = a1;
        W[(r0 + 2) * 400 + c] = a2; W[(r0 + 3) * 400 + c] = a3;
    }
}

// ---------------- kernel 1: QKV gemm. tile 128x64, thread 8x4, K-chunk 40 ----------------
// xs is XOR-swizzled (k ^= 4*(rowgrp&7)) so the 8-row-stride fp32 reads are bank-conflict-free.
__global__ __launch_bounds__(256, 3)
void k_qkv(const float* __restrict__ x, const float* __restrict__ kw,
           float* __restrict__ qo, float* __restrict__ ko, float* __restrict__ vo)
{
    __shared__ float xs[128 * 64];   // [128][64] swizzled, 40 k used
    __shared__ float wls[40 * 64];   // [40][64]
    const int ct = blockIdx.x;       // 0..4  (cols 0..319, >=300 masked)
    const int rt = blockIdx.y;       // 0..255
    const int row0 = rt * 128;
    const int tid = threadIdx.x;
    const int rg = tid >> 4, cg = tid & 15;
    const int sw = (rg & 7) << 2;
    float acc[8][4];
#pragma unroll
    for (int i = 0; i < 8; ++i)
#pragma unroll
        for (int j = 0; j < 4; ++j) acc[i][j] = 0.f;

    for (int it = 0; it < 10; ++it) {
        const int k0g = it * 40;
        __syncthreads();
        for (int i = tid; i < 1280; i += 256) {          // x tile [128][40] via float4
            int r = i / 10, k4 = i - r * 10;
            float4 t = *reinterpret_cast<const float4*>(
                &x[(size_t)(row0 + r) * 400 + k0g + k4 * 4]);
            int s = ((r >> 3) & 7) << 2;
            *reinterpret_cast<float4*>(&xs[(r << 6) + ((k4 * 4) ^ s)]) = t;
        }
        for (int i = tid; i < 640; i += 256) {           // w tile [40][64]
            int k = i >> 4, j4 = i & 15;
            int j0 = ct * 64 + j4 * 4;
            float4 t = make_float4(0.f, 0.f, 0.f, 0.f);
            if (j0 < 300) {
                int c = j0 >= 200 ? 2 : (j0 >= 100 ? 1 : 0);
                t = *reinterpret_cast<const float4*>(
                    &kw[c * 40000 + (k0g + k) * 100 + (j0 - c * 100)]);
            }
            *reinterpret_cast<float4*>(&wls[(k << 6) + j4 * 4]) = t;
        }
        __syncthreads();
        for (int k0 = 0; k0 < 40; k0 += 4) {
            float xf[8][4], wf[4][4];
#pragma unroll
            for (int i = 0; i < 8; ++i)
                load4(xf[i], &xs[((rg * 8 + i) << 6) + (k0 ^ sw)]);
#pragma unroll
            for (int m = 0; m < 4; ++m)
                load4(wf[m], &wls[((k0 + m) << 6) + cg * 4]);
#pragma unroll
            for (int i = 0; i < 8; ++i)
#pragma unroll
                for (int j = 0; j < 4; ++j)
                    acc[i][j] += xf[i][0] * wf[0][j] + xf[i][1] * wf[1][j]
                               + xf[i][2] * wf[2][j] + xf[i][3] * wf[3][j];
        }
    }
    const int j0 = ct * 64 + cg * 4;
    if (j0 < 300) {
        int c = j0 >= 200 ? 2 : (j0 >= 100 ? 1 : 0);
        float* dst = c == 0 ? qo : (c == 1 ? ko : vo);
        const int h0 = j0 - c * 100;
#pragma unroll
        for (int i = 0; i < 8; ++i) {
            float4 t;
            t.x = acc[i][0]; t.y = acc[i][1]; t.z = acc[i][2]; t.w = acc[i][3];
            *reinterpret_cast<float4*>(&dst[(size_t)(row0 + rg * 8 + i) * 100 + h0]) = t;
        }
    }
}

// ---------------- kernel 2: flash attention, QT=64, KT=64, 512 thr, 2 blk/CU ----------------
// q/head may alias (head overwrites this block's own q rows only) -> no __restrict__ on them.
__global__ __launch_bounds__(512, 4)
void k_flash(const float* q, const float* __restrict__ kin,
             const float* __restrict__ vin, float* head)
{
    __shared__ float q_s[64 * 108];   // [r][h] pad 108
    __shared__ float kv_s[6912];      // union: kT [100][68] | v [64][108]
    __shared__ float s_s[64 * 68];    // scores/p [r][kk] pad 68
    __shared__ float m_s[64], l_s[64], a_s[64];

    const int qt = blockIdx.x, b = blockIdx.y;
    const int tid = threadIdx.x;
    const int q0 = qt * 64;
    const size_t base = (size_t)b * (L_SEQ * HS);

    for (int i = tid; i < 1600; i += 512) {              // stage q (pre-scaled)
        int r = i / 25, h4 = i - r * 25;
        float4 t = *reinterpret_cast<const float4*>(&q[base + (size_t)(q0 + r) * 100 + h4 * 4]);
        t.x *= ATT_SCALE; t.y *= ATT_SCALE; t.z *= ATT_SCALE; t.w *= ATT_SCALE;
        *reinterpret_cast<float4*>(&q_s[r * 108 + h4 * 4]) = t;
    }
    if (tid < 64) { m_s[tid] = -1e30f; l_s[tid] = 0.f; }

    const int rgA = tid >> 4, cgA = tid & 15;            // phase A (tid<256): 4x4
    const int rgC = tid / 25, cgC = tid - rgC * 25;      // phase C (tid<400): 4 rows x 4 h
    float acc[4][4];
#pragma unroll
    for (int i = 0; i < 4; ++i)
#pragma unroll
        for (int j = 0; j < 4; ++j) acc[i][j] = 0.f;

    __syncthreads();

    for (int kt = 0; kt < 32; ++kt) {
        const int kb = kt * 64;
        for (int i = tid; i < 1600; i += 512) {          // stage k transposed: kT[h][r]
            int r = i / 25, h4 = i - r * 25;
            float4 t = *reinterpret_cast<const float4*>(
                &kin[base + (size_t)(kb + r) * 100 + h4 * 4]);
            kv_s[(h4 * 4 + 0) * 68 + r] = t.x;
            kv_s[(h4 * 4 + 1) * 68 + r] = t.y;
            kv_s[(h4 * 4 + 2) * 68 + r] = t.z;
            kv_s[(h4 * 4 + 3) * 68 + r] = t.w;
        }
        __syncthreads();
        if (tid < 256) {                                 // phase A: s = (q*scale) @ k^T
            float sa[4][4];
#pragma unroll
            for (int i = 0; i < 4; ++i)
#pragma unroll
                for (int j = 0; j < 4; ++j) sa[i][j] = 0.f;
            for (int h0 = 0; h0 < 100; h0 += 4) {
                float qf[4][4], kf[4][4];
#pragma unroll
                for (int i = 0; i < 4; ++i) load4(qf[i], &q_s[(rgA * 4 + i) * 108 + h0]);
#pragma unroll
                for (int m = 0; m < 4; ++m) load4(kf[m], &kv_s[(h0 + m) * 68 + cgA * 4]);
#pragma unroll
                for (int i = 0; i < 4; ++i)
#pragma unroll
                    for (int j = 0; j < 4; ++j)
                        sa[i][j] += qf[i][0] * kf[0][j] + qf[i][1] * kf[1][j]
                                  + qf[i][2] * kf[2][j] + qf[i][3] * kf[3][j];
            }
#pragma unroll
            for (int i = 0; i < 4; ++i)
#pragma unroll
                for (int j = 0; j < 4; ++j)
                    s_s[(rgA * 4 + i) * 68 + cgA * 4 + j] = sa[i][j];
        }
        __syncthreads();
        for (int i = tid; i < 1600; i += 512) {          // stage v [64][108] (over kT)
            int r = i / 25, h4 = i - r * 25;
            float4 t = *reinterpret_cast<const float4*>(
                &vin[base + (size_t)(kb + r) * 100 + h4 * 4]);
            *reinterpret_cast<float4*>(&kv_s[r * 108 + h4 * 4]) = t;
        }
        {                                                // phase B: online softmax (8 thr/row)
            const int r = tid >> 3, g = tid & 7;
            float4 u0 = *reinterpret_cast<const float4*>(&s_s[r * 68 + g * 8]);
            float4 u1 = *reinterpret_cast<const float4*>(&s_s[r * 68 + g * 8 + 4]);
            float mloc = fmaxf(fmaxf(fmaxf(u0.x, u0.y), fmaxf(u0.z, u0.w)),
                               fmaxf(fmaxf(u1.x, u1.y), fmaxf(u1.z, u1.w)));
            mloc = fmaxf(mloc, __shfl_xor(mloc, 1));
            mloc = fmaxf(mloc, __shfl_xor(mloc, 2));
            mloc = fmaxf(mloc, __shfl_xor(mloc, 4));
            float mo = m_s[r];
            float mn = fmaxf(mo, mloc);
            u0.x = __expf(u0.x - mn); u0.y = __expf(u0.y - mn);
            u0.z = __expf(u0.z - mn); u0.w = __expf(u0.w - mn);
            u1.x = __expf(u1.x - mn); u1.y = __expf(u1.y - mn);
            u1.z = __expf(u1.z - mn); u1.w = __expf(u1.w - mn);
            float ls = u0.x + u0.y + u0.z + u0.w + u1.x + u1.y + u1.z + u1.w;
            ls += __shfl_xor(ls, 1); ls += __shfl_xor(ls, 2); ls += __shfl_xor(ls, 4);
            *reinterpret_cast<float4*>(&s_s[r * 68 + g * 8]) = u0;
            *reinterpret_cast<float4*>(&s_s[r * 68 + g * 8 + 4]) = u1;
            if (g == 0) {
                float al = __expf(mo - mn);
                m_s[r] = mn; l_s[r] = l_s[r] * al + ls; a_s[r] = al;
            }
        }
        __syncthreads();
        if (tid < 400) {                                 // phase C: acc = acc*alpha + p @ v
            float alv[4];
#pragma unroll
            for (int i = 0; i < 4; ++i) alv[i] = a_s[rgC * 4 + i];
#pragma unroll
            for (int i = 0; i < 4; ++i)
#pragma unroll
                for (int j = 0; j < 4; ++j) acc[i][j] *= alv[i];
            for (int kk0 = 0; kk0 < 64; kk0 += 4) {
                float pf[4][4], vf[4][4];
#pragma unroll
                for (int i = 0; i < 4; ++i) load4(pf[i], &s_s[(rgC * 4 + i) * 68 + kk0]);
#pragma unroll
                for (int m = 0; m < 4; ++m) load4(vf[m], &kv_s[(kk0 + m) * 108 + cgC * 4]);
#pragma unroll
                for (int i = 0; i < 4; ++i)
#pragma unroll
                    for (int j = 0; j < 4; ++j)
                        acc[i][j] += pf[i][0] * vf[0][j] + pf[i][1] * vf[1][j]
                                   + pf[i][2] * vf[2][j] + pf[i][3] * vf[3][j];
            }
        }
        __syncthreads();
    }
    if (tid < 400) {                                     // head = acc / l
#pragma unroll
        for (int i = 0; i < 4; ++i) {
            float inv = 1.0f / l_s[rgC * 4 + i];
            float4 t;
            t.x = acc[i][0] * inv; t.y = acc[i][1] * inv;
            t.z = acc[i][2] * inv; t.w = acc[i][3] * inv;
            *reinterpret_cast<float4*>(
                &head[base + (size_t)(q0 + rgC * 4 + i) * 100 + cgC * 4]) = t;
        }
    }
}

// ---------------- kernel 3: h = relu(head@W + b2), per-block max/sum partials ----------------
__global__ __launch_bounds__(256, 3)
void k_hpool(const float* __restrict__ head, const float* __restrict__ W,
             const float* __restrict__ b2,
             float* __restrict__ pmax, float* __restrict__ psum)
{
    __shared__ float hs[64 * 108];
    __shared__ float wls[100 * 64];
    float* redm = wls;            // reuse wls after GEMM (barrier-protected)
    float* reds = wls + 1024;
    const int ct = blockIdx.x;    // 0..6 (cols 0..447, >=400 masked)
    const int rt = blockIdx.y;    // 0..511
    const int row0 = rt * 64, c0g = ct * 64;
    const int tid = threadIdx.x;
    const int rg = tid >> 4, cg = tid & 15;
    for (int i = tid; i < 1600; i += 256) {
        int r = i / 25, h4 = i - r * 25;
        float4 t = *reinterpret_cast<const float4*>(&head[(size_t)(row0 + r) * 100 + h4 * 4]);
        *reinterpret_cast<float4*>(&hs[r * 108 + h4 * 4]) = t;
    }
    for (int i = tid; i < 1600; i += 256) {
        int k = i >> 4, j4 = i & 15;
        int j0 = c0g + j4 * 4;
        float4 t = make_float4(0.f, 0.f, 0.f, 0.f);
        if (j0 < 400) t = *reinterpret_cast<const float4*>(&W[k * 400 + j0]);
        *reinterpret_cast<float4*>(&wls[(k << 6) + j4 * 4]) = t;
    }
    __syncthreads();
    float acc[4][4];
#pragma unroll
    for (int i = 0; i < 4; ++i)
#pragma unroll
        for (int j = 0; j < 4; ++j) acc[i][j] = 0.f;
    for (int k0 = 0; k0 < 100; k0 += 4) {
        float hf[4][4], wf[4][4];
#pragma unroll
        for (int i = 0; i < 4; ++i) load4(hf[i], &hs[(rg * 4 + i) * 108 + k0]);
#pragma unroll
        for (int m = 0; m < 4; ++m) load4(wf[m], &wls[((k0 + m) << 6) + cg * 4]);
#pragma unroll
        for (int i = 0; i < 4; ++i)
#pragma unroll
            for (int j = 0; j < 4; ++j)
                acc[i][j] += hf[i][0] * wf[0][j] + hf[i][1] * wf[1][j]
                           + hf[i][2] * wf[2][j] + hf[i][3] * wf[3][j];
    }
    __syncthreads();   // everyone done reading wls before redm/reds overwrite it
    {
        int cbase = c0g + cg * 4;
#pragma unroll
        for (int j = 0; j < 4; ++j) {
            int colg = cbase + j;
            float bv = colg < 400 ? b2[colg] : 0.f;
            float mx = 0.f, sm = 0.f;   // relu >= 0 so 0 is a safe max identity
#pragma unroll
            for (int i = 0; i < 4; ++i) {
                float hv = fmaxf(acc[i][j] + bv, 0.f);
                mx = fmaxf(mx, hv); sm += hv;
            }
            redm[rg * 64 + cg * 4 + j] = mx;
            reds[rg * 64 + cg * 4 + j] = sm;
        }
    }
    __syncthreads();
    if (tid < 64) {
        float mx = 0.f, sm = 0.f;
#pragma unroll
        for (int g = 0; g < 16; ++g) {
            mx = fmaxf(mx, redm[g * 64 + tid]);
            sm += reds[g * 64 + tid];
        }
        int colg = c0g + tid;
        if (colg < 400) {
            pmax[rt * 400 + colg] = mx;
            psum[rt * 400 + colg] = sm;
        }
    }
}

// ---------------- kernel 4: reduce partials + z=relu([max,avg]@w3+b3), out=relu(z@w4+b4) ----------------
__global__ __launch_bounds__(256)
void k_final(const float* __restrict__ pmax, const float* __restrict__ psum,
             const float* __restrict__ w3, const float* __restrict__ b3,
             const float* __restrict__ w4, const float* __restrict__ b4,
             float* __restrict__ out)
{
    __shared__ float zin[800];
    __shared__ float z1[512];
    const int b = blockIdx.x, tid = threadIdx.x;
    for (int c = tid; c < 400; c += 256) {
        float m = 0.f, s = 0.f;   // relu'd values -> max >= 0
        for (int tt = 0; tt < 32; ++tt) {
            m = fmaxf(m, pmax[(b * 32 + tt) * 400 + c]);
            s += psum[(b * 32 + tt) * 400 + c];
        }
        zin[c] = m;
        zin[400 + c] = s * (1.0f / 2048.0f);
    }
    __syncthreads();
    for (int c = tid; c < 512; c += 256) {
        float a = b3[c];
#pragma unroll 4
        for (int k = 0; k < 800; ++k) a += zin[k] * w3[k * 512 + c];
        z1[c] = fmaxf(a, 0.f);
    }
    __syncthreads();
    {
        float a = b4[tid];
#pragma unroll 4
        for (int k = 0; k < 512; ++k) a += z1[k] * w4[k * 256 + tid];
        out[b * 256 + tid] = fmaxf(a, 0.f);
    }
}

extern "C" void kernel_launch(void* const* d_in, const int* in_sizes, int n_in,
                              void* d_out, int out_size, void* d_ws, size_t ws_size,
                              hipStream_t stream) {
    (void)in_sizes; (void)n_in; (void)out_size; (void)ws_size;
    const float* x     = (const float*)d_in[0];
    const float* kw    = (const float*)d_in[1];
    const float* dense = (const float*)d_in[2];
    const float* w2    = (const float*)d_in[3];
    const float* b2    = (const float*)d_in[4];
    const float* w3    = (const float*)d_in[5];
    const float* b3    = (const float*)d_in[6];
    const float* w4    = (const float*)d_in[7];
    const float* b4    = (const float*)d_in[8];
    float* ws = (float*)d_ws;
    // workspace layout (floats); total 10,320,000 floats = 41.3 MB
    float* qbuf = ws;                    // [32768,100] q, later overwritten with head
    float* kbuf = ws + 3276800;
    float* vbuf = ws + 6553600;
    float* dsum = ws + 9830400;          // [100,400]
    float* Wb   = ws + 9870400;          // [100,400]
    float* pmax = ws + 9910400;          // [512,400]
    float* psum = ws + 10115200;         // [512,400]
    float* outp = (float*)d_out;

    k_dsum <<<dim3(157),      dim3(256), 0, stream>>>(dense, dsum);
    k_w    <<<dim3(25),       dim3(256), 0, stream>>>(dsum, w2, Wb);
    k_qkv  <<<dim3(5, 256),   dim3(256), 0, stream>>>(x, kw, qbuf, kbuf, vbuf);
    k_flash<<<dim3(32, 16),   dim3(512), 0, stream>>>(qbuf, kbuf, vbuf, qbuf);
    k_hpool<<<dim3(7, 512),   dim3(256), 0, stream>>>(qbuf, Wb, b2, pmax, psum);
    k_final<<<dim3(16),       dim3(256), 0, stream>>>(pmax, psum, w3, b3, w4, b4, outp);
}

// Round 2
// 538.054 us; speedup vs baseline: 1.6389x; 1.6389x over previous
//
#include <hip/hip_runtime.h>

// ExpertModuleTrm: B=16, L=2048, D=400, HS=100, heads=4 (identical -> 1 head).
// R1: flash attention on MFMA (bf16, Q hi/lo split, K/V/P single bf16).
//   QKV gemm outputs q_hi/q_lo/k_hi [32768][128] bf16 (h padded 100->128 with 0)
//   and vT [16][112][2048] bf16 (V transposed per batch, rows >=100 unwritten).
//   Flash: swapped QK^T (S^T = mfma(K,Q)) so softmax is lane-local + 2 shfl_xor;
//   P round-trips through per-wave LDS; PV reads vT as B-operand.
//   All LDS tiles XOR-swizzled on 16B granules -> conflict-free b128 frag reads.

#define L_SEQ 2048
#define HS    100
#define ATT_SCALE 0.1f

typedef __attribute__((ext_vector_type(8))) short bf16x8;
typedef __attribute__((ext_vector_type(4))) float f32x4;
#define MFMA16 __builtin_amdgcn_mfma_f32_16x16x32_bf16

__device__ __forceinline__ void load4(float (&d)[4], const float* p) {
    float4 t = *reinterpret_cast<const float4*>(p);
    d[0] = t.x; d[1] = t.y; d[2] = t.z; d[3] = t.w;
}

__device__ __forceinline__ ushort f2bf(float f) {   // fp32 -> bf16 RNE (finite)
    unsigned u = __float_as_uint(f);
    u += 0x7fffu + ((u >> 16) & 1u);
    return (ushort)(u >> 16);
}

// ---------------- kernel 0a: dsum[i,j] = sum_r dense[i+100r, j] ----------------
__global__ void k_dsum(const float* __restrict__ dense, float* __restrict__ dsum) {
    int t = blockIdx.x * 256 + threadIdx.x;
    if (t < 40000)
        dsum[t] = dense[t] + dense[t + 40000] + dense[t + 80000] + dense[t + 120000];
}

// ---------------- kernel 0b: W = dsum @ w2   [100,400]x[400,400] ----------------
__global__ __launch_bounds__(256)
void k_w(const float* __restrict__ dsum, const float* __restrict__ w2,
         float* __restrict__ W) {
    __shared__ float rows[4 * 400];
    const int r0 = blockIdx.x * 4;
    for (int i = threadIdx.x; i < 1600; i += 256) rows[i] = dsum[r0 * 400 + i];
    __syncthreads();
    for (int c = threadIdx.x; c < 400; c += 256) {
        float a0 = 0.f, a1 = 0.f, a2 = 0.f, a3 = 0.f;
#pragma unroll 4
        for (int k = 0; k < 400; ++k) {
            float wv = w2[k * 400 + c];
            a0 += rows[k] * wv;        a1 += rows[400 + k] * wv;
            a2 += rows[800 + k] * wv;  a3 += rows[1200 + k] * wv;
        }
        W[(r0 + 0) * 400 + c] = a0; W[(r0 + 1) * 400 + c] = a1;
        W[(r0 + 2) * 400 + c] = a2; W[(r0 + 3) * 400 + c] = a3;
    }
}

// ---------------- kernel 1: QKV gemm. tile 128x64, thread 8x4, K-chunk 40 ----------------
// col tiles ct 0..5 map j0 in [0,384): c=j0>>7 selects q/k/v, h0=j0&127 (h>=100 -> zeros).
// Outputs: q_hi/q_lo (scaled by ATT_SCALE, hi/lo split), k_hi (bf16), vT (bf16 transposed).
__global__ __launch_bounds__(256, 3)
void k_qkv(const float* __restrict__ x, const float* __restrict__ kw,
           ushort* __restrict__ q_hi, ushort* __restrict__ q_lo,
           ushort* __restrict__ k_hi, ushort* __restrict__ vT)
{
    __shared__ float xs[128 * 64];   // [128][64] swizzled, 40 k used
    __shared__ float wls[40 * 64];   // [40][64]
    const int ct = blockIdx.x;       // 0..5
    const int rt = blockIdx.y;       // 0..255
    const int row0 = rt * 128;
    const int tid = threadIdx.x;
    const int rg = tid >> 4, cg = tid & 15;
    const int sw = (rg & 7) << 2;
    float acc[8][4];
#pragma unroll
    for (int i = 0; i < 8; ++i)
#pragma unroll
        for (int j = 0; j < 4; ++j) acc[i][j] = 0.f;

    for (int it = 0; it < 10; ++it) {
        const int k0g = it * 40;
        __syncthreads();
        for (int i = tid; i < 1280; i += 256) {          // x tile [128][40] via float4
            int r = i / 10, k4 = i - r * 10;
            float4 t = *reinterpret_cast<const float4*>(
                &x[(size_t)(row0 + r) * 400 + k0g + k4 * 4]);
            int s = ((r >> 3) & 7) << 2;
            *reinterpret_cast<float4*>(&xs[(r << 6) + ((k4 * 4) ^ s)]) = t;
        }
        for (int i = tid; i < 640; i += 256) {           // w tile [40][64]
            int k = i >> 4, j4 = i & 15;
            int j0 = ct * 64 + j4 * 4;
            int c = j0 >> 7, h = j0 & 127;
            float4 t = make_float4(0.f, 0.f, 0.f, 0.f);
            if (h < 100)
                t = *reinterpret_cast<const float4*>(&kw[c * 40000 + (k0g + k) * 100 + h]);
            *reinterpret_cast<float4*>(&wls[(k << 6) + j4 * 4]) = t;
        }
        __syncthreads();
        for (int k0 = 0; k0 < 40; k0 += 4) {
            float xf[8][4], wf[4][4];
#pragma unroll
            for (int i = 0; i < 8; ++i)
                load4(xf[i], &xs[((rg * 8 + i) << 6) + (k0 ^ sw)]);
#pragma unroll
            for (int m = 0; m < 4; ++m)
                load4(wf[m], &wls[((k0 + m) << 6) + cg * 4]);
#pragma unroll
            for (int i = 0; i < 8; ++i)
#pragma unroll
                for (int j = 0; j < 4; ++j)
                    acc[i][j] += xf[i][0] * wf[0][j] + xf[i][1] * wf[1][j]
                               + xf[i][2] * wf[2][j] + xf[i][3] * wf[3][j];
        }
    }
    const int j0 = ct * 64 + cg * 4;
    const int c = j0 >> 7, h0 = j0 & 127;
    if (c == 0) {
#pragma unroll
        for (int i = 0; i < 8; ++i) {
            size_t row = (size_t)(row0 + rg * 8 + i);
            ushort4 hi4, lo4;
            float a0 = acc[i][0] * ATT_SCALE, a1 = acc[i][1] * ATT_SCALE;
            float a2 = acc[i][2] * ATT_SCALE, a3 = acc[i][3] * ATT_SCALE;
            hi4.x = f2bf(a0); hi4.y = f2bf(a1); hi4.z = f2bf(a2); hi4.w = f2bf(a3);
            lo4.x = f2bf(a0 - __uint_as_float((unsigned)hi4.x << 16));
            lo4.y = f2bf(a1 - __uint_as_float((unsigned)hi4.y << 16));
            lo4.z = f2bf(a2 - __uint_as_float((unsigned)hi4.z << 16));
            lo4.w = f2bf(a3 - __uint_as_float((unsigned)hi4.w << 16));
            *reinterpret_cast<ushort4*>(&q_hi[row * 128 + h0]) = hi4;
            *reinterpret_cast<ushort4*>(&q_lo[row * 128 + h0]) = lo4;
        }
    } else if (c == 1) {
#pragma unroll
        for (int i = 0; i < 8; ++i) {
            size_t row = (size_t)(row0 + rg * 8 + i);
            ushort4 hi4;
            hi4.x = f2bf(acc[i][0]); hi4.y = f2bf(acc[i][1]);
            hi4.z = f2bf(acc[i][2]); hi4.w = f2bf(acc[i][3]);
            *reinterpret_cast<ushort4*>(&k_hi[row * 128 + h0]) = hi4;
        }
    } else {
        const int bb = rt >> 4;
        const int keyl = (rt & 15) * 128 + rg * 8;
#pragma unroll
        for (int jj = 0; jj < 4; ++jj) {
            int h = h0 + jj;
            if (h < 100) {
                uint4 pk;
                unsigned* pw = reinterpret_cast<unsigned*>(&pk);
#pragma unroll
                for (int i = 0; i < 4; ++i)
                    pw[i] = (unsigned)f2bf(acc[2 * i][jj]) |
                            ((unsigned)f2bf(acc[2 * i + 1][jj]) << 16);
                *reinterpret_cast<uint4*>(&vT[((size_t)bb * 112 + h) * 2048 + keyl]) = pk;
            }
        }
    }
}

// ---------------- kernel 2: MFMA flash attention ----------------
// 4 waves x 16 q-rows, QT=64, KT=64, 32 KV steps. 2 blocks/CU.
__global__ __launch_bounds__(256, 2)
void k_flash(const ushort* __restrict__ q_hi, const ushort* __restrict__ q_lo,
             const ushort* __restrict__ k_hi, const ushort* __restrict__ vT,
             float* __restrict__ head)
{
    __shared__ __align__(16) ushort k_s[64 * 128];    // 16 KB, granule-swizzled
    __shared__ __align__(16) ushort vT_s[112 * 64];   // 14 KB, granule-swizzled
    __shared__ __align__(16) ushort p_s[4][16 * 64];  // 8 KB, per-wave P tiles

    const int id = blockIdx.x;                 // XCD swizzle: 512 = 8 XCD x 64
    const int Lg = (id & 7) * 64 + (id >> 3);
    const int qt = Lg & 31, b = Lg >> 5;
    const int q0 = qt * 64;
    const size_t bL = (size_t)b * L_SEQ;

    const int tid = threadIdx.x;
    const int lane = tid & 63, wv = tid >> 6;
    const int q15 = lane & 15, g0 = lane >> 4;

    // Q fragments (B operand): col=q15, k = 32*kh + 8*g0, direct from global
    bf16x8 qhf[4], qlf[4];
    {
        const ushort* qr = q_hi + (bL + q0 + 16 * wv + q15) * 128 + 8 * g0;
        const ushort* qs = q_lo + (bL + q0 + 16 * wv + q15) * 128 + 8 * g0;
#pragma unroll
        for (int kh = 0; kh < 4; ++kh) {
            qhf[kh] = *reinterpret_cast<const bf16x8*>(qr + 32 * kh);
            qlf[kh] = *reinterpret_cast<const bf16x8*>(qs + 32 * kh);
        }
    }

    float m_run = -1e30f, l_run = 0.f;
    f32x4 acc[7];
#pragma unroll
    for (int ht = 0; ht < 7; ++ht) acc[ht] = (f32x4){0.f, 0.f, 0.f, 0.f};

    for (int kt = 0; kt < 32; ++kt) {
        const int kb = kt * 64;
        __syncthreads();                               // prev compute done
        {   // stage K tile [64][128] bf16, swizzled granules
            const char* khg = (const char*)(k_hi + (bL + kb) * 128);
            for (int n = tid; n < 1024; n += 256) {
                int key = n >> 4, gg = n & 15;
                uint4 d = *reinterpret_cast<const uint4*>(khg + n * 16);
                *reinterpret_cast<uint4*>((char*)k_s + key * 256 + (((gg ^ (key & 15))) << 4)) = d;
            }
            // stage vT tile [112][64] bf16
            const char* vtg = (const char*)(vT + (size_t)b * 112 * 2048) + kb * 2;
            for (int n = tid; n < 896; n += 256) {
                int h = n >> 3, gg = n & 7;
                uint4 d = *reinterpret_cast<const uint4*>(vtg + h * 4096 + gg * 16);
                *reinterpret_cast<uint4*>((char*)vT_s + h * 128 + (((gg ^ (h & 7))) << 4)) = d;
            }
        }
        __syncthreads();

        // S^T = mfma(A=K, B=Q): tiles t over keys, kh over h=128
        f32x4 sacc[4];
        const int kx = q15 << 4;   // (key&15)<<4, key = 16t + q15
#pragma unroll
        for (int t = 0; t < 4; ++t) {
            sacc[t] = (f32x4){0.f, 0.f, 0.f, 0.f};
            const char* kr = (const char*)k_s + (t * 16 + q15) * 256;
#pragma unroll
            for (int kh = 0; kh < 4; ++kh) {
                bf16x8 kf = *reinterpret_cast<const bf16x8*>(kr + ((((kh << 2) + g0) << 4) ^ kx));
                sacc[t] = MFMA16(kf, qhf[kh], sacc[t], 0, 0, 0);
                sacc[t] = MFMA16(kf, qlf[kh], sacc[t], 0, 0, 0);
            }
        }

        // online softmax: lane holds S[key = 16t+4g0+r][q = q15]
        float mxl = -1e30f;
#pragma unroll
        for (int t = 0; t < 4; ++t)
#pragma unroll
            for (int r = 0; r < 4; ++r) mxl = fmaxf(mxl, sacc[t][r]);
        mxl = fmaxf(mxl, __shfl_xor(mxl, 16));
        mxl = fmaxf(mxl, __shfl_xor(mxl, 32));
        float mn = fmaxf(m_run, mxl);
        float alpha = __expf(m_run - mn);
        float lsum = 0.f;
        float p[4][4];
#pragma unroll
        for (int t = 0; t < 4; ++t)
#pragma unroll
            for (int r = 0; r < 4; ++r) {
                p[t][r] = __expf(sacc[t][r] - mn);
                lsum += p[t][r];
            }
        lsum += __shfl_xor(lsum, 16);
        lsum += __shfl_xor(lsum, 32);
        l_run = l_run * alpha + lsum;
        m_run = mn;
        float alv[4];
#pragma unroll
        for (int r = 0; r < 4; ++r) alv[r] = __shfl(alpha, (g0 << 2) | r);
#pragma unroll
        for (int ht = 0; ht < 7; ++ht)
#pragma unroll
            for (int r = 0; r < 4; ++r) acc[ht][r] *= alv[r];

        // P -> LDS (bf16), per-wave region, contiguous keys per write
        ushort* pw = p_s[wv];
        const int qb = q15 * 128;                       // row byte base (64 ushorts)
#pragma unroll
        for (int t = 0; t < 4; ++t) {
            ushort4 pv4;
            pv4.x = f2bf(p[t][0]); pv4.y = f2bf(p[t][1]);
            pv4.z = f2bf(p[t][2]); pv4.w = f2bf(p[t][3]);
            int gw = (t << 1) + (g0 >> 1);
            *reinterpret_cast<ushort4*>((char*)pw + qb + (((gw ^ (q15 & 7))) << 4)
                                        + ((g0 & 1) << 3)) = pv4;
        }

        // PV: A = P[q][key], B = vT[h][key]
        bf16x8 pa0 = *reinterpret_cast<const bf16x8*>((char*)pw + qb + (((g0 ^ (q15 & 7))) << 4));
        bf16x8 pa1 = *reinterpret_cast<const bf16x8*>((char*)pw + qb + ((((4 + g0) ^ (q15 & 7))) << 4));
#pragma unroll
        for (int ht = 0; ht < 7; ++ht) {
            const char* vr = (const char*)vT_s + (ht * 16 + q15) * 128;
            const int hx = ((ht * 16 + q15) & 7) << 4;
            bf16x8 vb0 = *reinterpret_cast<const bf16x8*>(vr + ((g0 << 4) ^ hx));
            bf16x8 vb1 = *reinterpret_cast<const bf16x8*>(vr + (((4 + g0) << 4) ^ hx));
            acc[ht] = MFMA16(pa0, vb0, acc[ht], 0, 0, 0);
            acc[ht] = MFMA16(pa1, vb1, acc[ht], 0, 0, 0);
        }
    }

    // epilogue: head[row][col] = acc / l
    float linv[4];
#pragma unroll
    for (int r = 0; r < 4; ++r) linv[r] = 1.0f / __shfl(l_run, (g0 << 2) | r);
#pragma unroll
    for (int ht = 0; ht < 7; ++ht) {
        int col = ht * 16 + q15;
        if (col < 100) {
            float* hp = head + (bL + q0 + 16 * wv + (g0 << 2)) * 100 + col;
#pragma unroll
            for (int r = 0; r < 4; ++r) hp[r * 100] = acc[ht][r] * linv[r];
        }
    }
}

// ---------------- kernel 3: h = relu(head@W + b2), per-block max/sum partials ----------------
__global__ __launch_bounds__(256, 3)
void k_hpool(const float* __restrict__ head, const float* __restrict__ W,
             const float* __restrict__ b2,
             float* __restrict__ pmax, float* __restrict__ psum)
{
    __shared__ float hs[64 * 108];
    __shared__ float wls[100 * 64];
    float* redm = wls;            // reuse wls after GEMM (barrier-protected)
    float* reds = wls + 1024;
    const int ct = blockIdx.x;    // 0..6 (cols 0..447, >=400 masked)
    const int rt = blockIdx.y;    // 0..511
    const int row0 = rt * 64, c0g = ct * 64;
    const int tid = threadIdx.x;
    const int rg = tid >> 4, cg = tid & 15;
    for (int i = tid; i < 1600; i += 256) {
        int r = i / 25, h4 = i - r * 25;
        float4 t = *reinterpret_cast<const float4*>(&head[(size_t)(row0 + r) * 100 + h4 * 4]);
        *reinterpret_cast<float4*>(&hs[r * 108 + h4 * 4]) = t;
    }
    for (int i = tid; i < 1600; i += 256) {
        int k = i >> 4, j4 = i & 15;
        int j0 = c0g + j4 * 4;
        float4 t = make_float4(0.f, 0.f, 0.f, 0.f);
        if (j0 < 400) t = *reinterpret_cast<const float4*>(&W[k * 400 + j0]);
        *reinterpret_cast<float4*>(&wls[(k << 6) + j4 * 4]) = t;
    }
    __syncthreads();
    float acc[4][4];
#pragma unroll
    for (int i = 0; i < 4; ++i)
#pragma unroll
        for (int j = 0; j < 4; ++j) acc[i][j] = 0.f;
    for (int k0 = 0; k0 < 100; k0 += 4) {
        float hf[4][4], wf[4][4];
#pragma unroll
        for (int i = 0; i < 4; ++i) load4(hf[i], &hs[(rg * 4 + i) * 108 + k0]);
#pragma unroll
        for (int m = 0; m < 4; ++m) load4(wf[m], &wls[((k0 + m) << 6) + cg * 4]);
#pragma unroll
        for (int i = 0; i < 4; ++i)
#pragma unroll
            for (int j = 0; j < 4; ++j)
                acc[i][j] += hf[i][0] * wf[0][j] + hf[i][1] * wf[1][j]
                           + hf[i][2] * wf[2][j] + hf[i][3] * wf[3][j];
    }
    __syncthreads();   // everyone done reading wls before redm/reds overwrite it
    {
        int cbase = c0g + cg * 4;
#pragma unroll
        for (int j = 0; j < 4; ++j) {
            int colg = cbase + j;
            float bv = colg < 400 ? b2[colg] : 0.f;
            float mx = 0.f, sm = 0.f;   // relu >= 0 so 0 is a safe max identity
#pragma unroll
            for (int i = 0; i < 4; ++i) {
                float hv = fmaxf(acc[i][j] + bv, 0.f);
                mx = fmaxf(mx, hv); sm += hv;
            }
            redm[rg * 64 + cg * 4 + j] = mx;
            reds[rg * 64 + cg * 4 + j] = sm;
        }
    }
    __syncthreads();
    if (tid < 64) {
        float mx = 0.f, sm = 0.f;
#pragma unroll
        for (int g = 0; g < 16; ++g) {
            mx = fmaxf(mx, redm[g * 64 + tid]);
            sm += reds[g * 64 + tid];
        }
        int colg = c0g + tid;
        if (colg < 400) {
            pmax[rt * 400 + colg] = mx;
            psum[rt * 400 + colg] = sm;
        }
    }
}

// ---------------- kernel 4: reduce partials + 2-layer MLP ----------------
__global__ __launch_bounds__(256)
void k_final(const float* __restrict__ pmax, const float* __restrict__ psum,
             const float* __restrict__ w3, const float* __restrict__ b3,
             const float* __restrict__ w4, const float* __restrict__ b4,
             float* __restrict__ out)
{
    __shared__ float zin[800];
    __shared__ float z1[512];
    const int b = blockIdx.x, tid = threadIdx.x;
    for (int c = tid; c < 400; c += 256) {
        float m = 0.f, s = 0.f;
        for (int tt = 0; tt < 32; ++tt) {
            m = fmaxf(m, pmax[(b * 32 + tt) * 400 + c]);
            s += psum[(b * 32 + tt) * 400 + c];
        }
        zin[c] = m;
        zin[400 + c] = s * (1.0f / 2048.0f);
    }
    __syncthreads();
    for (int c = tid; c < 512; c += 256) {
        float a = b3[c];
#pragma unroll 4
        for (int k = 0; k < 800; ++k) a += zin[k] * w3[k * 512 + c];
        z1[c] = fmaxf(a, 0.f);
    }
    __syncthreads();
    {
        float a = b4[tid];
#pragma unroll 4
        for (int k = 0; k < 512; ++k) a += z1[k] * w4[k * 256 + tid];
        out[b * 256 + tid] = fmaxf(a, 0.f);
    }
}

extern "C" void kernel_launch(void* const* d_in, const int* in_sizes, int n_in,
                              void* d_out, int out_size, void* d_ws, size_t ws_size,
                              hipStream_t stream) {
    (void)in_sizes; (void)n_in; (void)out_size; (void)ws_size;
    const float* x     = (const float*)d_in[0];
    const float* kw    = (const float*)d_in[1];
    const float* dense = (const float*)d_in[2];
    const float* w2    = (const float*)d_in[3];
    const float* b2    = (const float*)d_in[4];
    const float* w3    = (const float*)d_in[5];
    const float* b3    = (const float*)d_in[6];
    const float* w4    = (const float*)d_in[7];
    const float* b4    = (const float*)d_in[8];
    float* ws = (float*)d_ws;
    // workspace layout (float units), total 11,483,264 floats = 45.9 MB
    ushort* q_hi = (ushort*)(ws);                 // [32768][128] bf16
    ushort* q_lo = (ushort*)(ws + 2097152);
    ushort* k_hi = (ushort*)(ws + 4194304);
    ushort* vT   = (ushort*)(ws + 6291456);       // [16][112][2048] bf16
    float*  head = ws + 8126464;                  // [32768][100] f32
    float*  dsum = ws + 11403264;                 // [100][400]
    float*  Wb   = ws + 11443264;                 // [100][400]
    float*  pmax = ws;                            // overlay on q_hi (dead after flash)
    float*  psum = ws + 204800;
    float*  outp = (float*)d_out;

    k_dsum <<<dim3(157),      dim3(256), 0, stream>>>(dense, dsum);
    k_w    <<<dim3(25),       dim3(256), 0, stream>>>(dsum, w2, Wb);
    k_qkv  <<<dim3(6, 256),   dim3(256), 0, stream>>>(x, kw, q_hi, q_lo, k_hi, vT);
    k_flash<<<dim3(512),      dim3(256), 0, stream>>>(q_hi, q_lo, k_hi, vT, head);
    k_hpool<<<dim3(7, 512),   dim3(256), 0, stream>>>(head, Wb, b2, pmax, psum);
    k_final<<<dim3(16),       dim3(256), 0, stream>>>(pmax, psum, w3, b3, w4, b4, outp);
}

// Round 3
// 381.046 us; speedup vs baseline: 2.3142x; 1.4120x over previous
//
#include <hip/hip_runtime.h>

// ExpertModuleTrm: B=16, L=2048, D=400, HS=100, heads=4 (identical -> 1 head).
// R2: flash attention on MFMA (unchanged from R1); the latency-bound tail
//   (k_final, 220us @ 0.7% occupancy) split into k_reduce/k_mlp1/k_mlp2 with
//   split-k + LDS reduction; k_w likewise split-k across 175 blocks.

#define L_SEQ 2048
#define HS    100
#define ATT_SCALE 0.1f

typedef __attribute__((ext_vector_type(8))) short bf16x8;
typedef __attribute__((ext_vector_type(4))) float f32x4;
#define MFMA16 __builtin_amdgcn_mfma_f32_16x16x32_bf16

__device__ __forceinline__ void load4(float (&d)[4], const float* p) {
    float4 t = *reinterpret_cast<const float4*>(p);
    d[0] = t.x; d[1] = t.y; d[2] = t.z; d[3] = t.w;
}

__device__ __forceinline__ ushort f2bf(float f) {   // fp32 -> bf16 RNE (finite)
    unsigned u = __float_as_uint(f);
    u += 0x7fffu + ((u >> 16) & 1u);
    return (ushort)(u >> 16);
}

// ---------------- kernel 0a: dsum[i,j] = sum_r dense[i+100r, j] ----------------
__global__ void k_dsum(const float* __restrict__ dense, float* __restrict__ dsum) {
    int t = blockIdx.x * 256 + threadIdx.x;
    if (t < 40000)
        dsum[t] = dense[t] + dense[t + 40000] + dense[t + 80000] + dense[t + 120000];
}

// ---------------- kernel 0b: W = dsum @ w2, split-k x4, grid (7,25) ----------------
__global__ __launch_bounds__(256)
void k_w(const float* __restrict__ dsum, const float* __restrict__ w2,
         float* __restrict__ W) {
    __shared__ float rows[4 * 400];
    __shared__ float red[4][4][64];
    const int cb = blockIdx.x;        // 0..6 (col group, 64 wide, >=400 masked)
    const int r0 = blockIdx.y * 4;    // 0..96
    const int tid = threadIdx.x;
    const int c = tid & 63, kk = tid >> 6;
    const int col = cb * 64 + c;
    for (int i = tid; i < 1600; i += 256) rows[i] = dsum[r0 * 400 + i];
    __syncthreads();
    float a0 = 0.f, a1 = 0.f, a2 = 0.f, a3 = 0.f;
    if (col < 400) {
        const int kbase = kk * 100;
#pragma unroll 4
        for (int k = 0; k < 100; ++k) {
            float wv = w2[(kbase + k) * 400 + col];
            a0 += rows[kbase + k] * wv;
            a1 += rows[400 + kbase + k] * wv;
            a2 += rows[800 + kbase + k] * wv;
            a3 += rows[1200 + kbase + k] * wv;
        }
    }
    red[kk][0][c] = a0; red[kk][1][c] = a1; red[kk][2][c] = a2; red[kk][3][c] = a3;
    __syncthreads();
    {
        const int r = kk;   // 4 rows handled by the 4 kk groups
        float s = red[0][r][c] + red[1][r][c] + red[2][r][c] + red[3][r][c];
        if (col < 400) W[(r0 + r) * 400 + col] = s;
    }
}

// ---------------- kernel 1: QKV gemm. tile 128x64, thread 8x4, K-chunk 40 ----------------
// col tiles ct 0..5 map j0 in [0,384): c=j0>>7 selects q/k/v, h0=j0&127 (h>=100 -> zeros).
// Outputs: q_hi/q_lo (scaled by ATT_SCALE, hi/lo split), k_hi (bf16), vT (bf16 transposed).
__global__ __launch_bounds__(256, 3)
void k_qkv(const float* __restrict__ x, const float* __restrict__ kw,
           ushort* __restrict__ q_hi, ushort* __restrict__ q_lo,
           ushort* __restrict__ k_hi, ushort* __restrict__ vT)
{
    __shared__ float xs[128 * 64];   // [128][64] swizzled, 40 k used
    __shared__ float wls[40 * 64];   // [40][64]
    const int ct = blockIdx.x;       // 0..5
    const int rt = blockIdx.y;       // 0..255
    const int row0 = rt * 128;
    const int tid = threadIdx.x;
    const int rg = tid >> 4, cg = tid & 15;
    const int sw = (rg & 7) << 2;
    float acc[8][4];
#pragma unroll
    for (int i = 0; i < 8; ++i)
#pragma unroll
        for (int j = 0; j < 4; ++j) acc[i][j] = 0.f;

    for (int it = 0; it < 10; ++it) {
        const int k0g = it * 40;
        __syncthreads();
        for (int i = tid; i < 1280; i += 256) {          // x tile [128][40] via float4
            int r = i / 10, k4 = i - r * 10;
            float4 t = *reinterpret_cast<const float4*>(
                &x[(size_t)(row0 + r) * 400 + k0g + k4 * 4]);
            int s = ((r >> 3) & 7) << 2;
            *reinterpret_cast<float4*>(&xs[(r << 6) + ((k4 * 4) ^ s)]) = t;
        }
        for (int i = tid; i < 640; i += 256) {           // w tile [40][64]
            int k = i >> 4, j4 = i & 15;
            int j0 = ct * 64 + j4 * 4;
            int c = j0 >> 7, h = j0 & 127;
            float4 t = make_float4(0.f, 0.f, 0.f, 0.f);
            if (h < 100)
                t = *reinterpret_cast<const float4*>(&kw[c * 40000 + (k0g + k) * 100 + h]);
            *reinterpret_cast<float4*>(&wls[(k << 6) + j4 * 4]) = t;
        }
        __syncthreads();
        for (int k0 = 0; k0 < 40; k0 += 4) {
            float xf[8][4], wf[4][4];
#pragma unroll
            for (int i = 0; i < 8; ++i)
                load4(xf[i], &xs[((rg * 8 + i) << 6) + (k0 ^ sw)]);
#pragma unroll
            for (int m = 0; m < 4; ++m)
                load4(wf[m], &wls[((k0 + m) << 6) + cg * 4]);
#pragma unroll
            for (int i = 0; i < 8; ++i)
#pragma unroll
                for (int j = 0; j < 4; ++j)
                    acc[i][j] += xf[i][0] * wf[0][j] + xf[i][1] * wf[1][j]
                               + xf[i][2] * wf[2][j] + xf[i][3] * wf[3][j];
        }
    }
    const int j0 = ct * 64 + cg * 4;
    const int c = j0 >> 7, h0 = j0 & 127;
    if (c == 0) {
#pragma unroll
        for (int i = 0; i < 8; ++i) {
            size_t row = (size_t)(row0 + rg * 8 + i);
            ushort4 hi4, lo4;
            float a0 = acc[i][0] * ATT_SCALE, a1 = acc[i][1] * ATT_SCALE;
            float a2 = acc[i][2] * ATT_SCALE, a3 = acc[i][3] * ATT_SCALE;
            hi4.x = f2bf(a0); hi4.y = f2bf(a1); hi4.z = f2bf(a2); hi4.w = f2bf(a3);
            lo4.x = f2bf(a0 - __uint_as_float((unsigned)hi4.x << 16));
            lo4.y = f2bf(a1 - __uint_as_float((unsigned)hi4.y << 16));
            lo4.z = f2bf(a2 - __uint_as_float((unsigned)hi4.z << 16));
            lo4.w = f2bf(a3 - __uint_as_float((unsigned)hi4.w << 16));
            *reinterpret_cast<ushort4*>(&q_hi[row * 128 + h0]) = hi4;
            *reinterpret_cast<ushort4*>(&q_lo[row * 128 + h0]) = lo4;
        }
    } else if (c == 1) {
#pragma unroll
        for (int i = 0; i < 8; ++i) {
            size_t row = (size_t)(row0 + rg * 8 + i);
            ushort4 hi4;
            hi4.x = f2bf(acc[i][0]); hi4.y = f2bf(acc[i][1]);
            hi4.z = f2bf(acc[i][2]); hi4.w = f2bf(acc[i][3]);
            *reinterpret_cast<ushort4*>(&k_hi[row * 128 + h0]) = hi4;
        }
    } else {
        const int bb = rt >> 4;
        const int keyl = (rt & 15) * 128 + rg * 8;
#pragma unroll
        for (int jj = 0; jj < 4; ++jj) {
            int h = h0 + jj;
            if (h < 100) {
                uint4 pk;
                unsigned* pw = reinterpret_cast<unsigned*>(&pk);
#pragma unroll
                for (int i = 0; i < 4; ++i)
                    pw[i] = (unsigned)f2bf(acc[2 * i][jj]) |
                            ((unsigned)f2bf(acc[2 * i + 1][jj]) << 16);
                *reinterpret_cast<uint4*>(&vT[((size_t)bb * 112 + h) * 2048 + keyl]) = pk;
            }
        }
    }
}

// ---------------- kernel 2: MFMA flash attention ----------------
// 4 waves x 16 q-rows, QT=64, KT=64, 32 KV steps. 2 blocks/CU.
__global__ __launch_bounds__(256, 2)
void k_flash(const ushort* __restrict__ q_hi, const ushort* __restrict__ q_lo,
             const ushort* __restrict__ k_hi, const ushort* __restrict__ vT,
             float* __restrict__ head)
{
    __shared__ __align__(16) ushort k_s[64 * 128];    // 16 KB, granule-swizzled
    __shared__ __align__(16) ushort vT_s[112 * 64];   // 14 KB, granule-swizzled
    __shared__ __align__(16) ushort p_s[4][16 * 64];  // 8 KB, per-wave P tiles

    const int id = blockIdx.x;                 // XCD swizzle: 512 = 8 XCD x 64
    const int Lg = (id & 7) * 64 + (id >> 3);
    const int qt = Lg & 31, b = Lg >> 5;
    const int q0 = qt * 64;
    const size_t bL = (size_t)b * L_SEQ;

    const int tid = threadIdx.x;
    const int lane = tid & 63, wv = tid >> 6;
    const int q15 = lane & 15, g0 = lane >> 4;

    // Q fragments (B operand): col=q15, k = 32*kh + 8*g0, direct from global
    bf16x8 qhf[4], qlf[4];
    {
        const ushort* qr = q_hi + (bL + q0 + 16 * wv + q15) * 128 + 8 * g0;
        const ushort* qs = q_lo + (bL + q0 + 16 * wv + q15) * 128 + 8 * g0;
#pragma unroll
        for (int kh = 0; kh < 4; ++kh) {
            qhf[kh] = *reinterpret_cast<const bf16x8*>(qr + 32 * kh);
            qlf[kh] = *reinterpret_cast<const bf16x8*>(qs + 32 * kh);
        }
    }

    float m_run = -1e30f, l_run = 0.f;
    f32x4 acc[7];
#pragma unroll
    for (int ht = 0; ht < 7; ++ht) acc[ht] = (f32x4){0.f, 0.f, 0.f, 0.f};

    for (int kt = 0; kt < 32; ++kt) {
        const int kb = kt * 64;
        __syncthreads();                               // prev compute done
        {   // stage K tile [64][128] bf16, swizzled granules
            const char* khg = (const char*)(k_hi + (bL + kb) * 128);
            for (int n = tid; n < 1024; n += 256) {
                int key = n >> 4, gg = n & 15;
                uint4 d = *reinterpret_cast<const uint4*>(khg + n * 16);
                *reinterpret_cast<uint4*>((char*)k_s + key * 256 + (((gg ^ (key & 15))) << 4)) = d;
            }
            // stage vT tile [112][64] bf16
            const char* vtg = (const char*)(vT + (size_t)b * 112 * 2048) + kb * 2;
            for (int n = tid; n < 896; n += 256) {
                int h = n >> 3, gg = n & 7;
                uint4 d = *reinterpret_cast<const uint4*>(vtg + h * 4096 + gg * 16);
                *reinterpret_cast<uint4*>((char*)vT_s + h * 128 + (((gg ^ (h & 7))) << 4)) = d;
            }
        }
        __syncthreads();

        // S^T = mfma(A=K, B=Q): tiles t over keys, kh over h=128
        f32x4 sacc[4];
        const int kx = q15 << 4;   // (key&15)<<4, key = 16t + q15
#pragma unroll
        for (int t = 0; t < 4; ++t) {
            sacc[t] = (f32x4){0.f, 0.f, 0.f, 0.f};
            const char* kr = (const char*)k_s + (t * 16 + q15) * 256;
#pragma unroll
            for (int kh = 0; kh < 4; ++kh) {
                bf16x8 kf = *reinterpret_cast<const bf16x8*>(kr + ((((kh << 2) + g0) << 4) ^ kx));
                sacc[t] = MFMA16(kf, qhf[kh], sacc[t], 0, 0, 0);
                sacc[t] = MFMA16(kf, qlf[kh], sacc[t], 0, 0, 0);
            }
        }

        // online softmax: lane holds S[key = 16t+4g0+r][q = q15]
        float mxl = -1e30f;
#pragma unroll
        for (int t = 0; t < 4; ++t)
#pragma unroll
            for (int r = 0; r < 4; ++r) mxl = fmaxf(mxl, sacc[t][r]);
        mxl = fmaxf(mxl, __shfl_xor(mxl, 16));
        mxl = fmaxf(mxl, __shfl_xor(mxl, 32));
        float mn = fmaxf(m_run, mxl);
        float alpha = __expf(m_run - mn);
        float lsum = 0.f;
        float p[4][4];
#pragma unroll
        for (int t = 0; t < 4; ++t)
#pragma unroll
            for (int r = 0; r < 4; ++r) {
                p[t][r] = __expf(sacc[t][r] - mn);
                lsum += p[t][r];
            }
        lsum += __shfl_xor(lsum, 16);
        lsum += __shfl_xor(lsum, 32);
        l_run = l_run * alpha + lsum;
        m_run = mn;
        float alv[4];
#pragma unroll
        for (int r = 0; r < 4; ++r) alv[r] = __shfl(alpha, (g0 << 2) | r);
#pragma unroll
        for (int ht = 0; ht < 7; ++ht)
#pragma unroll
            for (int r = 0; r < 4; ++r) acc[ht][r] *= alv[r];

        // P -> LDS (bf16), per-wave region, contiguous keys per write
        ushort* pw = p_s[wv];
        const int qb = q15 * 128;                       // row byte base (64 ushorts)
#pragma unroll
        for (int t = 0; t < 4; ++t) {
            ushort4 pv4;
            pv4.x = f2bf(p[t][0]); pv4.y = f2bf(p[t][1]);
            pv4.z = f2bf(p[t][2]); pv4.w = f2bf(p[t][3]);
            int gw = (t << 1) + (g0 >> 1);
            *reinterpret_cast<ushort4*>((char*)pw + qb + (((gw ^ (q15 & 7))) << 4)
                                        + ((g0 & 1) << 3)) = pv4;
        }

        // PV: A = P[q][key], B = vT[h][key]
        bf16x8 pa0 = *reinterpret_cast<const bf16x8*>((char*)pw + qb + (((g0 ^ (q15 & 7))) << 4));
        bf16x8 pa1 = *reinterpret_cast<const bf16x8*>((char*)pw + qb + ((((4 + g0) ^ (q15 & 7))) << 4));
#pragma unroll
        for (int ht = 0; ht < 7; ++ht) {
            const char* vr = (const char*)vT_s + (ht * 16 + q15) * 128;
            const int hx = ((ht * 16 + q15) & 7) << 4;
            bf16x8 vb0 = *reinterpret_cast<const bf16x8*>(vr + ((g0 << 4) ^ hx));
            bf16x8 vb1 = *reinterpret_cast<const bf16x8*>(vr + (((4 + g0) << 4) ^ hx));
            acc[ht] = MFMA16(pa0, vb0, acc[ht], 0, 0, 0);
            acc[ht] = MFMA16(pa1, vb1, acc[ht], 0, 0, 0);
        }
    }

    // epilogue: head[row][col] = acc / l
    float linv[4];
#pragma unroll
    for (int r = 0; r < 4; ++r) linv[r] = 1.0f / __shfl(l_run, (g0 << 2) | r);
#pragma unroll
    for (int ht = 0; ht < 7; ++ht) {
        int col = ht * 16 + q15;
        if (col < 100) {
            float* hp = head + (bL + q0 + 16 * wv + (g0 << 2)) * 100 + col;
#pragma unroll
            for (int r = 0; r < 4; ++r) hp[r * 100] = acc[ht][r] * linv[r];
        }
    }
}

// ---------------- kernel 3: h = relu(head@W + b2), per-block max/sum partials ----------------
__global__ __launch_bounds__(256, 3)
void k_hpool(const float* __restrict__ head, const float* __restrict__ W,
             const float* __restrict__ b2,
             float* __restrict__ pmax, float* __restrict__ psum)
{
    __shared__ float hs[64 * 108];
    __shared__ float wls[100 * 64];
    float* redm = wls;            // reuse wls after GEMM (barrier-protected)
    float* reds = wls + 1024;
    const int ct = blockIdx.x;    // 0..6 (cols 0..447, >=400 masked)
    const int rt = blockIdx.y;    // 0..511
    const int row0 = rt * 64, c0g = ct * 64;
    const int tid = threadIdx.x;
    const int rg = tid >> 4, cg = tid & 15;
    for (int i = tid; i < 1600; i += 256) {
        int r = i / 25, h4 = i - r * 25;
        float4 t = *reinterpret_cast<const float4*>(&head[(size_t)(row0 + r) * 100 + h4 * 4]);
        *reinterpret_cast<float4*>(&hs[r * 108 + h4 * 4]) = t;
    }
    for (int i = tid; i < 1600; i += 256) {
        int k = i >> 4, j4 = i & 15;
        int j0 = c0g + j4 * 4;
        float4 t = make_float4(0.f, 0.f, 0.f, 0.f);
        if (j0 < 400) t = *reinterpret_cast<const float4*>(&W[k * 400 + j0]);
        *reinterpret_cast<float4*>(&wls[(k << 6) + j4 * 4]) = t;
    }
    __syncthreads();
    float acc[4][4];
#pragma unroll
    for (int i = 0; i < 4; ++i)
#pragma unroll
        for (int j = 0; j < 4; ++j) acc[i][j] = 0.f;
    for (int k0 = 0; k0 < 100; k0 += 4) {
        float hf[4][4], wf[4][4];
#pragma unroll
        for (int i = 0; i < 4; ++i) load4(hf[i], &hs[(rg * 4 + i) * 108 + k0]);
#pragma unroll
        for (int m = 0; m < 4; ++m) load4(wf[m], &wls[((k0 + m) << 6) + cg * 4]);
#pragma unroll
        for (int i = 0; i < 4; ++i)
#pragma unroll
            for (int j = 0; j < 4; ++j)
                acc[i][j] += hf[i][0] * wf[0][j] + hf[i][1] * wf[1][j]
                           + hf[i][2] * wf[2][j] + hf[i][3] * wf[3][j];
    }
    __syncthreads();   // everyone done reading wls before redm/reds overwrite it
    {
        int cbase = c0g + cg * 4;
#pragma unroll
        for (int j = 0; j < 4; ++j) {
            int colg = cbase + j;
            float bv = colg < 400 ? b2[colg] : 0.f;
            float mx = 0.f, sm = 0.f;   // relu >= 0 so 0 is a safe max identity
#pragma unroll
            for (int i = 0; i < 4; ++i) {
                float hv = fmaxf(acc[i][j] + bv, 0.f);
                mx = fmaxf(mx, hv); sm += hv;
            }
            redm[rg * 64 + cg * 4 + j] = mx;
            reds[rg * 64 + cg * 4 + j] = sm;
        }
    }
    __syncthreads();
    if (tid < 64) {
        float mx = 0.f, sm = 0.f;
#pragma unroll
        for (int g = 0; g < 16; ++g) {
            mx = fmaxf(mx, redm[g * 64 + tid]);
            sm += reds[g * 64 + tid];
        }
        int colg = c0g + tid;
        if (colg < 400) {
            pmax[rt * 400 + colg] = mx;
            psum[rt * 400 + colg] = sm;
        }
    }
}

// ---------------- kernel 4a: reduce 32 partials -> zin[16][800] ----------------
__global__ __launch_bounds__(512)
void k_reduce(const float* __restrict__ pmax, const float* __restrict__ psum,
              float* __restrict__ zin)
{
    const int b = blockIdx.x, c = threadIdx.x;
    if (c < 400) {
        float m = 0.f, s = 0.f;
#pragma unroll
        for (int tt = 0; tt < 32; ++tt) {
            m = fmaxf(m, pmax[(b * 32 + tt) * 400 + c]);
            s += psum[(b * 32 + tt) * 400 + c];
        }
        zin[b * 800 + c] = m;
        zin[b * 800 + 400 + c] = s * (1.0f / 2048.0f);
    }
}

// ---------------- kernel 4b: z1 = relu(zin @ w3 + b3), split-k x8 ----------------
__global__ __launch_bounds__(512)
void k_mlp1(const float* __restrict__ zin, const float* __restrict__ w3,
            const float* __restrict__ b3, float* __restrict__ z1)
{
    __shared__ float zs[800];
    __shared__ float red[8][64];
    const int cb = blockIdx.x, b = blockIdx.y;
    const int tid = threadIdx.x;
    const int c = tid & 63, kk = tid >> 6;
    const int col = cb * 64 + c;
    for (int i = tid; i < 800; i += 512) zs[i] = zin[b * 800 + i];
    __syncthreads();
    float acc = 0.f;
    const int k0 = kk * 100;
#pragma unroll 4
    for (int k = 0; k < 100; ++k)
        acc += zs[k0 + k] * w3[(k0 + k) * 512 + col];
    red[kk][c] = acc;
    __syncthreads();
    if (kk == 0) {
        float a = b3[col];
#pragma unroll
        for (int g = 0; g < 8; ++g) a += red[g][c];
        z1[b * 512 + col] = fmaxf(a, 0.f);
    }
}

// ---------------- kernel 4c: out = relu(z1 @ w4 + b4), split-k x8 ----------------
__global__ __launch_bounds__(512)
void k_mlp2(const float* __restrict__ z1, const float* __restrict__ w4,
            const float* __restrict__ b4, float* __restrict__ out)
{
    __shared__ float zs[512];
    __shared__ float red[8][64];
    const int cb = blockIdx.x, b = blockIdx.y;
    const int tid = threadIdx.x;
    const int c = tid & 63, kk = tid >> 6;
    const int col = cb * 64 + c;
    if (tid < 512) zs[tid] = z1[b * 512 + tid];
    __syncthreads();
    float acc = 0.f;
    const int k0 = kk * 64;
#pragma unroll 4
    for (int k = 0; k < 64; ++k)
        acc += zs[k0 + k] * w4[(k0 + k) * 256 + col];
    red[kk][c] = acc;
    __syncthreads();
    if (kk == 0) {
        float a = b4[col];
#pragma unroll
        for (int g = 0; g < 8; ++g) a += red[g][c];
        out[b * 256 + col] = fmaxf(a, 0.f);
    }
}

extern "C" void kernel_launch(void* const* d_in, const int* in_sizes, int n_in,
                              void* d_out, int out_size, void* d_ws, size_t ws_size,
                              hipStream_t stream) {
    (void)in_sizes; (void)n_in; (void)out_size; (void)ws_size;
    const float* x     = (const float*)d_in[0];
    const float* kw    = (const float*)d_in[1];
    const float* dense = (const float*)d_in[2];
    const float* w2    = (const float*)d_in[3];
    const float* b2    = (const float*)d_in[4];
    const float* w3    = (const float*)d_in[5];
    const float* b3    = (const float*)d_in[6];
    const float* w4    = (const float*)d_in[7];
    const float* b4    = (const float*)d_in[8];
    float* ws = (float*)d_ws;
    // workspace layout (float units), total 11,504,256 floats = 46.0 MB
    ushort* q_hi = (ushort*)(ws);                 // [32768][128] bf16
    ushort* q_lo = (ushort*)(ws + 2097152);
    ushort* k_hi = (ushort*)(ws + 4194304);
    ushort* vT   = (ushort*)(ws + 6291456);       // [16][112][2048] bf16
    float*  head = ws + 8126464;                  // [32768][100] f32
    float*  dsum = ws + 11403264;                 // [100][400]
    float*  Wb   = ws + 11443264;                 // [100][400]
    float*  zin  = ws + 11483264;                 // [16][800]
    float*  z1   = ws + 11496064;                 // [16][512]
    float*  pmax = ws;                            // overlay on q_hi (dead after flash)
    float*  psum = ws + 204800;
    float*  outp = (float*)d_out;

    k_dsum  <<<dim3(157),      dim3(256), 0, stream>>>(dense, dsum);
    k_w     <<<dim3(7, 25),    dim3(256), 0, stream>>>(dsum, w2, Wb);
    k_qkv   <<<dim3(6, 256),   dim3(256), 0, stream>>>(x, kw, q_hi, q_lo, k_hi, vT);
    k_flash <<<dim3(512),      dim3(256), 0, stream>>>(q_hi, q_lo, k_hi, vT, head);
    k_hpool <<<dim3(7, 512),   dim3(256), 0, stream>>>(head, Wb, b2, pmax, psum);
    k_reduce<<<dim3(16),       dim3(512), 0, stream>>>(pmax, psum, zin);
    k_mlp1  <<<dim3(8, 16),    dim3(512), 0, stream>>>(zin, w3, b3, z1);
    k_mlp2  <<<dim3(4, 16),    dim3(512), 0, stream>>>(z1, w4, b4, outp);
}

// Round 4
// 251.077 us; speedup vs baseline: 3.5122x; 1.5176x over previous
//
#include <hip/hip_runtime.h>

// ExpertModuleTrm: B=16, L=2048, D=400, HS=100, heads=4 (identical -> 1 head).
// R3: QKV gemm + hpool gemm moved to MFMA with 3-product bf16 hi/lo split
//   (xh*wh + xl*wh + xh*wl ~ fp32 accuracy). Weights pre-split/transposed:
//   wT_hi/wT_lo [384][448] for QKV (q cols pre-scaled), WT_hi/WT_lo [448][128]
//   for hpool. x/head converted to hi/lo bf16 in XOR-swizzled LDS in-kernel.
//   Flash attention unchanged from R2.

#define L_SEQ 2048
#define HS    100
#define ATT_SCALE 0.1f

typedef __attribute__((ext_vector_type(8))) short bf16x8;
typedef __attribute__((ext_vector_type(4))) float f32x4;
#define MFMA16 __builtin_amdgcn_mfma_f32_16x16x32_bf16

__device__ __forceinline__ ushort f2bf(float f) {   // fp32 -> bf16 RNE (finite)
    unsigned u = __float_as_uint(f);
    u += 0x7fffu + ((u >> 16) & 1u);
    return (ushort)(u >> 16);
}
__device__ __forceinline__ float bfval(ushort u) {
    return __uint_as_float((unsigned)u << 16);
}

// ---------------- kernel 0a: dsum[i,j] = sum_r dense[i+100r, j] ----------------
__global__ void k_dsum(const float* __restrict__ dense, float* __restrict__ dsum) {
    int t = blockIdx.x * 256 + threadIdx.x;
    if (t < 40000)
        dsum[t] = dense[t] + dense[t + 40000] + dense[t + 80000] + dense[t + 120000];
}

// ---- kernel 0b: WT = (dsum @ w2)^T as bf16 hi/lo [448][128], zero-padded ----
__global__ __launch_bounds__(256)
void k_w(const float* __restrict__ dsum, const float* __restrict__ w2,
         ushort* __restrict__ WT_hi, ushort* __restrict__ WT_lo) {
    __shared__ float rows[4 * 400];
    __shared__ float red[4][4][64];
    const int cb = blockIdx.x;        // 0..6 (col group, 64 wide)
    const int r0 = blockIdx.y * 4;    // 0..124
    const int tid = threadIdx.x;
    const int c = tid & 63, kk = tid >> 6;
    const int col = cb * 64 + c;
    for (int i = tid; i < 1600; i += 256) {
        int rr = r0 + i / 400;
        rows[i] = (rr < 100) ? dsum[r0 * 400 + i] : 0.f;
    }
    __syncthreads();
    float a0 = 0.f, a1 = 0.f, a2 = 0.f, a3 = 0.f;
    if (col < 400) {
        const int kbase = kk * 100;
#pragma unroll 4
        for (int k = 0; k < 100; ++k) {
            float wv = w2[(kbase + k) * 400 + col];
            a0 += rows[kbase + k] * wv;
            a1 += rows[400 + kbase + k] * wv;
            a2 += rows[800 + kbase + k] * wv;
            a3 += rows[1200 + kbase + k] * wv;
        }
    }
    red[kk][0][c] = a0; red[kk][1][c] = a1; red[kk][2][c] = a2; red[kk][3][c] = a3;
    __syncthreads();
    {
        const int r = kk;
        float s = red[0][r][c] + red[1][r][c] + red[2][r][c] + red[3][r][c];
        ushort hi = f2bf(s);
        WT_hi[col * 128 + r0 + r] = hi;
        WT_lo[col * 128 + r0 + r] = f2bf(s - bfval(hi));
    }
}

// ---- kernel 0c: wT_hi/lo[j=(c,h)][k] bf16 from kernel[3][400][100], q scaled ----
__global__ __launch_bounds__(448)
void k_wprep(const float* __restrict__ kw,
             ushort* __restrict__ wT_hi, ushort* __restrict__ wT_lo) {
    const int j = blockIdx.x;          // 0..383
    const int c = j >> 7, h = j & 127;
    const int k = threadIdx.x;         // 0..447
    float v = 0.f;
    if (h < 100 && k < 400) v = kw[c * 40000 + k * 100 + h];
    if (c == 0) v *= ATT_SCALE;
    ushort hi = f2bf(v);
    wT_hi[(size_t)j * 448 + k] = hi;
    wT_lo[(size_t)j * 448 + k] = f2bf(v - bfval(hi));
}

// ---------------- kernel 1: MFMA QKV gemm ----------------
// 256 blocks x 128 rows. 8 waves = 4 colgroups(96) x 2 rowgroups(64).
// Swapped operands: D[m=col][n=row] = mfma(A=wT, B=x). x cvt to hi/lo in LDS.
__global__ __launch_bounds__(512, 2)
void k_qkv(const float* __restrict__ x,
           const ushort* __restrict__ wT_hi, const ushort* __restrict__ wT_lo,
           ushort* __restrict__ q_hi, ushort* __restrict__ q_lo,
           ushort* __restrict__ k_hi, ushort* __restrict__ vT)
{
    __shared__ __align__(16) ushort xh_s[128 * 64];
    __shared__ __align__(16) ushort xl_s[128 * 64];
    const int row0 = blockIdx.x << 7;
    const int bb = row0 >> 11;
    const int tid = threadIdx.x;
    const int lane = tid & 63, wv = tid >> 6;
    const int q15 = lane & 15, g0 = lane >> 4;
    const int cW = (wv & 3) * 96, rW = (wv >> 2) * 64;

    f32x4 acc[6][4];
#pragma unroll
    for (int mf = 0; mf < 6; ++mf)
#pragma unroll
        for (int nf = 0; nf < 4; ++nf) acc[mf][nf] = (f32x4){0.f, 0.f, 0.f, 0.f};

    float4 st[4];
#define QKV_STAGE_LOAD(KC)                                                     \
    _Pragma("unroll") for (int i = 0; i < 4; ++i) {                            \
        int idx = tid + i * 512; int r = idx >> 4, c4 = idx & 15;              \
        int g = (KC) * 64 + c4 * 4;                                            \
        st[i] = (g <= 396) ? *reinterpret_cast<const float4*>(                 \
                                 &x[(size_t)(row0 + r) * 400 + g])             \
                           : make_float4(0.f, 0.f, 0.f, 0.f);                  \
    }
#define QKV_STAGE_WRITE()                                                      \
    _Pragma("unroll") for (int i = 0; i < 4; ++i) {                            \
        int idx = tid + i * 512; int r = idx >> 4, c4 = idx & 15;              \
        ushort4 hi4, lo4;                                                      \
        hi4.x = f2bf(st[i].x); lo4.x = f2bf(st[i].x - bfval(hi4.x));           \
        hi4.y = f2bf(st[i].y); lo4.y = f2bf(st[i].y - bfval(hi4.y));           \
        hi4.z = f2bf(st[i].z); lo4.z = f2bf(st[i].z - bfval(hi4.z));           \
        hi4.w = f2bf(st[i].w); lo4.w = f2bf(st[i].w - bfval(hi4.w));           \
        int off = r * 128 + ((c4 * 8) ^ ((r & 7) << 4));                       \
        *reinterpret_cast<ushort4*>((char*)xh_s + off) = hi4;                  \
        *reinterpret_cast<ushort4*>((char*)xl_s + off) = lo4;                  \
    }

    QKV_STAGE_LOAD(0)
    QKV_STAGE_WRITE()
    __syncthreads();

    for (int kc = 0; kc < 7; ++kc) {
        if (kc < 6) { QKV_STAGE_LOAD(kc + 1) }         // T14: issue early
#pragma unroll
        for (int k2 = 0; k2 < 2; ++k2) {
            const int k0 = kc * 64 + k2 * 32;
            bf16x8 bh[4], bl[4];
#pragma unroll
            for (int nf = 0; nf < 4; ++nf) {
                int row = rW + nf * 16 + q15;
                int boff = row * 128 + ((k2 * 64 + g0 * 16) ^ ((row & 7) << 4));
                bh[nf] = *reinterpret_cast<const bf16x8*>((char*)xh_s + boff);
                bl[nf] = *reinterpret_cast<const bf16x8*>((char*)xl_s + boff);
            }
#pragma unroll
            for (int mf = 0; mf < 6; ++mf) {
                int col = cW + mf * 16 + q15;
                bf16x8 ah = *reinterpret_cast<const bf16x8*>(
                    wT_hi + (size_t)col * 448 + k0 + g0 * 8);
                bf16x8 al = *reinterpret_cast<const bf16x8*>(
                    wT_lo + (size_t)col * 448 + k0 + g0 * 8);
#pragma unroll
                for (int nf = 0; nf < 4; ++nf) {
                    acc[mf][nf] = MFMA16(ah, bh[nf], acc[mf][nf], 0, 0, 0);
                    acc[mf][nf] = MFMA16(ah, bl[nf], acc[mf][nf], 0, 0, 0);
                    acc[mf][nf] = MFMA16(al, bh[nf], acc[mf][nf], 0, 0, 0);
                }
            }
        }
        __syncthreads();
        if (kc < 6) {
            QKV_STAGE_WRITE()
            __syncthreads();
        }
    }

    // epilogue: lane holds cols col0..col0+3 for row (q/k packed, vT scatter)
#pragma unroll
    for (int mf = 0; mf < 6; ++mf) {
        const int col0 = cW + mf * 16 + 4 * g0;
        const int c = col0 >> 7, h0 = col0 & 127;
#pragma unroll
        for (int nf = 0; nf < 4; ++nf) {
            const size_t row = (size_t)(row0 + rW + nf * 16 + q15);
            if (c == 0) {
                ushort4 hi4, lo4;
#pragma unroll
                for (int r = 0; r < 4; ++r) {
                    float vf = acc[mf][nf][r];
                    ushort h = f2bf(vf);
                    ((ushort*)&hi4)[r] = h;
                    ((ushort*)&lo4)[r] = f2bf(vf - bfval(h));
                }
                *reinterpret_cast<ushort4*>(&q_hi[row * 128 + h0]) = hi4;
                *reinterpret_cast<ushort4*>(&q_lo[row * 128 + h0]) = lo4;
            } else if (c == 1) {
                ushort4 hi4;
#pragma unroll
                for (int r = 0; r < 4; ++r) ((ushort*)&hi4)[r] = f2bf(acc[mf][nf][r]);
                *reinterpret_cast<ushort4*>(&k_hi[row * 128 + h0]) = hi4;
            } else {
                const int keyl = (int)row & 2047;
#pragma unroll
                for (int jj = 0; jj < 4; ++jj) {
                    int h = h0 + jj;
                    if (h < 100)
                        vT[((size_t)bb * 112 + h) * 2048 + keyl] = f2bf(acc[mf][nf][jj]);
                }
            }
        }
    }
#undef QKV_STAGE_LOAD
#undef QKV_STAGE_WRITE
}

// ---------------- kernel 2: MFMA flash attention (unchanged from R2) ----------------
__global__ __launch_bounds__(256, 2)
void k_flash(const ushort* __restrict__ q_hi, const ushort* __restrict__ q_lo,
             const ushort* __restrict__ k_hi, const ushort* __restrict__ vT,
             float* __restrict__ head)
{
    __shared__ __align__(16) ushort k_s[64 * 128];
    __shared__ __align__(16) ushort vT_s[112 * 64];
    __shared__ __align__(16) ushort p_s[4][16 * 64];

    const int id = blockIdx.x;                 // XCD swizzle: 512 = 8 XCD x 64
    const int Lg = (id & 7) * 64 + (id >> 3);
    const int qt = Lg & 31, b = Lg >> 5;
    const int q0 = qt * 64;
    const size_t bL = (size_t)b * L_SEQ;

    const int tid = threadIdx.x;
    const int lane = tid & 63, wv = tid >> 6;
    const int q15 = lane & 15, g0 = lane >> 4;

    bf16x8 qhf[4], qlf[4];
    {
        const ushort* qr = q_hi + (bL + q0 + 16 * wv + q15) * 128 + 8 * g0;
        const ushort* qs = q_lo + (bL + q0 + 16 * wv + q15) * 128 + 8 * g0;
#pragma unroll
        for (int kh = 0; kh < 4; ++kh) {
            qhf[kh] = *reinterpret_cast<const bf16x8*>(qr + 32 * kh);
            qlf[kh] = *reinterpret_cast<const bf16x8*>(qs + 32 * kh);
        }
    }

    float m_run = -1e30f, l_run = 0.f;
    f32x4 acc[7];
#pragma unroll
    for (int ht = 0; ht < 7; ++ht) acc[ht] = (f32x4){0.f, 0.f, 0.f, 0.f};

    for (int kt = 0; kt < 32; ++kt) {
        const int kb = kt * 64;
        __syncthreads();
        {
            const char* khg = (const char*)(k_hi + (bL + kb) * 128);
            for (int n = tid; n < 1024; n += 256) {
                int key = n >> 4, gg = n & 15;
                uint4 d = *reinterpret_cast<const uint4*>(khg + n * 16);
                *reinterpret_cast<uint4*>((char*)k_s + key * 256 + (((gg ^ (key & 15))) << 4)) = d;
            }
            const char* vtg = (const char*)(vT + (size_t)b * 112 * 2048) + kb * 2;
            for (int n = tid; n < 896; n += 256) {
                int h = n >> 3, gg = n & 7;
                uint4 d = *reinterpret_cast<const uint4*>(vtg + h * 4096 + gg * 16);
                *reinterpret_cast<uint4*>((char*)vT_s + h * 128 + (((gg ^ (h & 7))) << 4)) = d;
            }
        }
        __syncthreads();

        f32x4 sacc[4];
        const int kx = q15 << 4;
#pragma unroll
        for (int t = 0; t < 4; ++t) {
            sacc[t] = (f32x4){0.f, 0.f, 0.f, 0.f};
            const char* kr = (const char*)k_s + (t * 16 + q15) * 256;
#pragma unroll
            for (int kh = 0; kh < 4; ++kh) {
                bf16x8 kf = *reinterpret_cast<const bf16x8*>(kr + ((((kh << 2) + g0) << 4) ^ kx));
                sacc[t] = MFMA16(kf, qhf[kh], sacc[t], 0, 0, 0);
                sacc[t] = MFMA16(kf, qlf[kh], sacc[t], 0, 0, 0);
            }
        }

        float mxl = -1e30f;
#pragma unroll
        for (int t = 0; t < 4; ++t)
#pragma unroll
            for (int r = 0; r < 4; ++r) mxl = fmaxf(mxl, sacc[t][r]);
        mxl = fmaxf(mxl, __shfl_xor(mxl, 16));
        mxl = fmaxf(mxl, __shfl_xor(mxl, 32));
        float mn = fmaxf(m_run, mxl);
        float alpha = __expf(m_run - mn);
        float lsum = 0.f;
        float p[4][4];
#pragma unroll
        for (int t = 0; t < 4; ++t)
#pragma unroll
            for (int r = 0; r < 4; ++r) {
                p[t][r] = __expf(sacc[t][r] - mn);
                lsum += p[t][r];
            }
        lsum += __shfl_xor(lsum, 16);
        lsum += __shfl_xor(lsum, 32);
        l_run = l_run * alpha + lsum;
        m_run = mn;
        float alv[4];
#pragma unroll
        for (int r = 0; r < 4; ++r) alv[r] = __shfl(alpha, (g0 << 2) | r);
#pragma unroll
        for (int ht = 0; ht < 7; ++ht)
#pragma unroll
            for (int r = 0; r < 4; ++r) acc[ht][r] *= alv[r];

        ushort* pw = p_s[wv];
        const int qb = q15 * 128;
#pragma unroll
        for (int t = 0; t < 4; ++t) {
            ushort4 pv4;
            pv4.x = f2bf(p[t][0]); pv4.y = f2bf(p[t][1]);
            pv4.z = f2bf(p[t][2]); pv4.w = f2bf(p[t][3]);
            int gw = (t << 1) + (g0 >> 1);
            *reinterpret_cast<ushort4*>((char*)pw + qb + (((gw ^ (q15 & 7))) << 4)
                                        + ((g0 & 1) << 3)) = pv4;
        }

        bf16x8 pa0 = *reinterpret_cast<const bf16x8*>((char*)pw + qb + (((g0 ^ (q15 & 7))) << 4));
        bf16x8 pa1 = *reinterpret_cast<const bf16x8*>((char*)pw + qb + ((((4 + g0) ^ (q15 & 7))) << 4));
#pragma unroll
        for (int ht = 0; ht < 7; ++ht) {
            const char* vr = (const char*)vT_s + (ht * 16 + q15) * 128;
            const int hx = ((ht * 16 + q15) & 7) << 4;
            bf16x8 vb0 = *reinterpret_cast<const bf16x8*>(vr + ((g0 << 4) ^ hx));
            bf16x8 vb1 = *reinterpret_cast<const bf16x8*>(vr + (((4 + g0) << 4) ^ hx));
            acc[ht] = MFMA16(pa0, vb0, acc[ht], 0, 0, 0);
            acc[ht] = MFMA16(pa1, vb1, acc[ht], 0, 0, 0);
        }
    }

    float linv[4];
#pragma unroll
    for (int r = 0; r < 4; ++r) linv[r] = 1.0f / __shfl(l_run, (g0 << 2) | r);
#pragma unroll
    for (int ht = 0; ht < 7; ++ht) {
        int col = ht * 16 + q15;
        if (col < 100) {
            float* hp = head + (bL + q0 + 16 * wv + (g0 << 2)) * 100 + col;
#pragma unroll
            for (int r = 0; r < 4; ++r) hp[r * 100] = acc[ht][r] * linv[r];
        }
    }
}

// ---------------- kernel 3: MFMA hpool: h=relu(head@W+b2) + max/sum partials ----------------
// 256 blocks x 128 rows; 8 waves = 2 rowgroups(64) x 4 colgroups(112).
__global__ __launch_bounds__(512, 2)
void k_hpool(const float* __restrict__ head,
             const ushort* __restrict__ WT_hi, const ushort* __restrict__ WT_lo,
             const float* __restrict__ b2,
             float* __restrict__ pmax, float* __restrict__ psum)
{
    __shared__ __align__(16) ushort hh_s[128 * 128];
    __shared__ __align__(16) ushort hl_s[128 * 128];
    __shared__ float pm_s[8][112], ps_s[8][112];
    const int blk = blockIdx.x;
    const int row0 = blk << 7;
    const int tid = threadIdx.x;
    const int lane = tid & 63, wv = tid >> 6;
    const int q15 = lane & 15, g0 = lane >> 4;
    const int wvM = wv >> 2, wvN = wv & 3;

    for (int i = 0; i < 7; ++i) {                 // stage head -> hi/lo LDS
        int idx = tid + i * 512;
        if (idx < 3200) {
            int r = idx / 25, cc = idx - r * 25;
            float4 t = *reinterpret_cast<const float4*>(
                &head[(size_t)(row0 + r) * 100 + cc * 4]);
            ushort4 hi4, lo4;
            hi4.x = f2bf(t.x); lo4.x = f2bf(t.x - bfval(hi4.x));
            hi4.y = f2bf(t.y); lo4.y = f2bf(t.y - bfval(hi4.y));
            hi4.z = f2bf(t.z); lo4.z = f2bf(t.z - bfval(hi4.z));
            hi4.w = f2bf(t.w); lo4.w = f2bf(t.w - bfval(hi4.w));
            int off = r * 256 + ((cc * 8) ^ ((r & 7) << 4));
            *reinterpret_cast<ushort4*>((char*)hh_s + off) = hi4;
            *reinterpret_cast<ushort4*>((char*)hl_s + off) = lo4;
        }
    }
    for (int idx = tid; idx < 896; idx += 512) {  // zero-pad k 100..127
        int r = idx / 7, c7 = idx - r * 7;
        int off = r * 256 + (((200 + c7 * 8)) ^ ((r & 7) << 4));
        ushort4 z = {0, 0, 0, 0};
        *reinterpret_cast<ushort4*>((char*)hh_s + off) = z;
        *reinterpret_cast<ushort4*>((char*)hl_s + off) = z;
    }
    __syncthreads();

    f32x4 acc[4][7];
#pragma unroll
    for (int mf = 0; mf < 4; ++mf)
#pragma unroll
        for (int nf = 0; nf < 7; ++nf) acc[mf][nf] = (f32x4){0.f, 0.f, 0.f, 0.f};

#pragma unroll
    for (int ks = 0; ks < 4; ++ks) {
        const int k0 = ks * 32;
        bf16x8 ah[4], al[4];
#pragma unroll
        for (int mf = 0; mf < 4; ++mf) {
            int rowL = wvM * 64 + mf * 16 + q15;
            int aoff = rowL * 256 + ((k0 * 2 + g0 * 16) ^ ((rowL & 7) << 4));
            ah[mf] = *reinterpret_cast<const bf16x8*>((char*)hh_s + aoff);
            al[mf] = *reinterpret_cast<const bf16x8*>((char*)hl_s + aoff);
        }
#pragma unroll
        for (int nf = 0; nf < 7; ++nf) {
            int col = wvN * 112 + nf * 16 + q15;
            bf16x8 bh = *reinterpret_cast<const bf16x8*>(WT_hi + col * 128 + k0 + g0 * 8);
            bf16x8 bl = *reinterpret_cast<const bf16x8*>(WT_lo + col * 128 + k0 + g0 * 8);
#pragma unroll
            for (int mf = 0; mf < 4; ++mf) {
                acc[mf][nf] = MFMA16(ah[mf], bh, acc[mf][nf], 0, 0, 0);
                acc[mf][nf] = MFMA16(ah[mf], bl, acc[mf][nf], 0, 0, 0);
                acc[mf][nf] = MFMA16(al[mf], bh, acc[mf][nf], 0, 0, 0);
            }
        }
    }

    // pooling epilogue: relu(acc+b2) -> per-wave col partials
#pragma unroll
    for (int nf = 0; nf < 7; ++nf) {
        int col = wvN * 112 + nf * 16 + q15;
        float bv = (col < 400) ? b2[col] : 0.f;
        float mx = 0.f, sm = 0.f;
#pragma unroll
        for (int mf = 0; mf < 4; ++mf)
#pragma unroll
            for (int r = 0; r < 4; ++r) {
                float hv = fmaxf(acc[mf][nf][r] + bv, 0.f);
                mx = fmaxf(mx, hv); sm += hv;
            }
        mx = fmaxf(mx, __shfl_xor(mx, 16));
        mx = fmaxf(mx, __shfl_xor(mx, 32));
        sm += __shfl_xor(sm, 16);
        sm += __shfl_xor(sm, 32);
        if (g0 == 0) {
            pm_s[wv][nf * 16 + q15] = mx;
            ps_s[wv][nf * 16 + q15] = sm;
        }
    }
    __syncthreads();
    if (tid < 448) {
        int wn = tid / 112, cc = tid - wn * 112;
        float mx = fmaxf(pm_s[wn][cc], pm_s[4 + wn][cc]);
        float sm = ps_s[wn][cc] + ps_s[4 + wn][cc];
        if (tid < 400) {
            pmax[blk * 400 + tid] = mx;
            psum[blk * 400 + tid] = sm;
        }
    }
}

// ---------------- kernel 4a: reduce 16 partials -> zin[16][800] ----------------
__global__ __launch_bounds__(512)
void k_reduce(const float* __restrict__ pmax, const float* __restrict__ psum,
              float* __restrict__ zin)
{
    const int b = blockIdx.x, c = threadIdx.x;
    if (c < 400) {
        float m = 0.f, s = 0.f;
#pragma unroll
        for (int tt = 0; tt < 16; ++tt) {
            m = fmaxf(m, pmax[(b * 16 + tt) * 400 + c]);
            s += psum[(b * 16 + tt) * 400 + c];
        }
        zin[b * 800 + c] = m;
        zin[b * 800 + 400 + c] = s * (1.0f / 2048.0f);
    }
}

// ---------------- kernel 4b: z1 = relu(zin @ w3 + b3), split-k x8 ----------------
__global__ __launch_bounds__(512)
void k_mlp1(const float* __restrict__ zin, const float* __restrict__ w3,
            const float* __restrict__ b3, float* __restrict__ z1)
{
    __shared__ float zs[800];
    __shared__ float red[8][64];
    const int cb = blockIdx.x, b = blockIdx.y;
    const int tid = threadIdx.x;
    const int c = tid & 63, kk = tid >> 6;
    const int col = cb * 64 + c;
    for (int i = tid; i < 800; i += 512) zs[i] = zin[b * 800 + i];
    __syncthreads();
    float acc = 0.f;
    const int k0 = kk * 100;
#pragma unroll 4
    for (int k = 0; k < 100; ++k)
        acc += zs[k0 + k] * w3[(k0 + k) * 512 + col];
    red[kk][c] = acc;
    __syncthreads();
    if (kk == 0) {
        float a = b3[col];
#pragma unroll
        for (int g = 0; g < 8; ++g) a += red[g][c];
        z1[b * 512 + col] = fmaxf(a, 0.f);
    }
}

// ---------------- kernel 4c: out = relu(z1 @ w4 + b4), split-k x8 ----------------
__global__ __launch_bounds__(512)
void k_mlp2(const float* __restrict__ z1, const float* __restrict__ w4,
            const float* __restrict__ b4, float* __restrict__ out)
{
    __shared__ float zs[512];
    __shared__ float red[8][64];
    const int cb = blockIdx.x, b = blockIdx.y;
    const int tid = threadIdx.x;
    const int c = tid & 63, kk = tid >> 6;
    const int col = cb * 64 + c;
    if (tid < 512) zs[tid] = z1[b * 512 + tid];
    __syncthreads();
    float acc = 0.f;
    const int k0 = kk * 64;
#pragma unroll 4
    for (int k = 0; k < 64; ++k)
        acc += zs[k0 + k] * w4[(k0 + k) * 256 + col];
    red[kk][c] = acc;
    __syncthreads();
    if (kk == 0) {
        float a = b4[col];
#pragma unroll
        for (int g = 0; g < 8; ++g) a += red[g][c];
        out[b * 256 + col] = fmaxf(a, 0.f);
    }
}

extern "C" void kernel_launch(void* const* d_in, const int* in_sizes, int n_in,
                              void* d_out, int out_size, void* d_ws, size_t ws_size,
                              hipStream_t stream) {
    (void)in_sizes; (void)n_in; (void)out_size; (void)ws_size;
    const float* x     = (const float*)d_in[0];
    const float* kw    = (const float*)d_in[1];
    const float* dense = (const float*)d_in[2];
    const float* w2    = (const float*)d_in[3];
    const float* b2    = (const float*)d_in[4];
    const float* w3    = (const float*)d_in[5];
    const float* b3    = (const float*)d_in[6];
    const float* w4    = (const float*)d_in[7];
    const float* b4    = (const float*)d_in[8];
    float* ws = (float*)d_ws;
    // workspace layout (float units), total 11,460,608 floats = 45.8 MB
    ushort* q_hi = (ushort*)(ws);                 // [32768][128] bf16
    ushort* q_lo = (ushort*)(ws + 2097152);
    ushort* k_hi = (ushort*)(ws + 4194304);
    ushort* vT   = (ushort*)(ws + 6291456);       // [16][112][2048] bf16
    float*  head = ws + 8126464;                  // [32768][100] f32
    // overlays (lifetimes disjoint, stream-ordered):
    float*  dsum  = ws;                           // dead before k_qkv writes q_hi
    ushort* wT_hi = (ushort*)(ws + 8126464);      // overlays head; dead before k_flash
    ushort* wT_lo = (ushort*)(ws + 8212480);
    ushort* WT_hi = (ushort*)(ws + 11403264);     // [448][128] bf16, lives to k_hpool
    ushort* WT_lo = (ushort*)(ws + 11431936);
    float*  pmax = ws;                            // overlays q_hi (dead after flash)
    float*  psum = ws + 2097152;                  // overlays q_lo
    float*  zin  = ws + 4194304;                  // overlays k_hi
    float*  z1   = ws + 4207104;
    float*  outp = (float*)d_out;

    k_dsum  <<<dim3(157),      dim3(256), 0, stream>>>(dense, dsum);
    k_w     <<<dim3(7, 32),    dim3(256), 0, stream>>>(dsum, w2, WT_hi, WT_lo);
    k_wprep <<<dim3(384),      dim3(448), 0, stream>>>(kw, wT_hi, wT_lo);
    k_qkv   <<<dim3(256),      dim3(512), 0, stream>>>(x, wT_hi, wT_lo,
                                                       q_hi, q_lo, k_hi, vT);
    k_flash <<<dim3(512),      dim3(256), 0, stream>>>(q_hi, q_lo, k_hi, vT, head);
    k_hpool <<<dim3(256),      dim3(512), 0, stream>>>(head, WT_hi, WT_lo, b2,
                                                       pmax, psum);
    k_reduce<<<dim3(16),       dim3(512), 0, stream>>>(pmax, psum, zin);
    k_mlp1  <<<dim3(8, 16),    dim3(512), 0, stream>>>(zin, w3, b3, z1);
    k_mlp2  <<<dim3(4, 16),    dim3(512), 0, stream>>>(z1, w4, b4, outp);
}